// Round 1
// 1099.847 us; speedup vs baseline: 1.0135x; 1.0135x over previous
//
#include <hip/hip_runtime.h>
#include <cstddef>

#define L_SEQ 1024
#define B_SZ  128
#define D_SZ  256
#define H_SZ  256

// ---------------------------------------------------------------------------
// Kernel 1: xproj GEMM (unchanged -- control)
// ---------------------------------------------------------------------------
#define KT  16
#define LDA 132

__global__ __launch_bounds__(256) void xproj_gemm(
    const float* __restrict__ x, const float* __restrict__ Wx,
    const float* __restrict__ bx, float* __restrict__ out)
{
    __shared__ float sA[KT][LDA];
    __shared__ float sB[KT][LDA];

    const int tm  = blockIdx.x;
    const int tn  = blockIdx.y;
    const int tid = threadIdx.x;
    const int tx  = tid & 15;
    const int ty  = tid >> 4;
    const int srow = tid >> 2;
    const int skq  = tid & 3;

    const float* __restrict__ Ag = x  + (size_t)(tm * 128 + srow) * D_SZ + skq * 4;
    const float* __restrict__ Bg = Wx + (size_t)(tn * 128 + srow) * D_SZ + skq * 4;

    float c[2][2][4][4];
    #pragma unroll
    for (int mc = 0; mc < 2; ++mc)
        #pragma unroll
        for (int nc = 0; nc < 2; ++nc)
            #pragma unroll
            for (int i = 0; i < 4; ++i)
                #pragma unroll
                for (int j = 0; j < 4; ++j) c[mc][nc][i][j] = 0.0f;

    for (int kt = 0; kt < D_SZ / KT; ++kt) {
        float4 av0 = *reinterpret_cast<const float4*>(Ag + kt * KT);
        float4 av1 = *reinterpret_cast<const float4*>(Ag + (size_t)64 * D_SZ + kt * KT);
        float4 bv0 = *reinterpret_cast<const float4*>(Bg + kt * KT);
        float4 bv1 = *reinterpret_cast<const float4*>(Bg + (size_t)64 * D_SZ + kt * KT);
        __syncthreads();
        sA[skq * 4 + 0][srow] = av0.x; sA[skq * 4 + 1][srow] = av0.y;
        sA[skq * 4 + 2][srow] = av0.z; sA[skq * 4 + 3][srow] = av0.w;
        sA[skq * 4 + 0][64 + srow] = av1.x; sA[skq * 4 + 1][64 + srow] = av1.y;
        sA[skq * 4 + 2][64 + srow] = av1.z; sA[skq * 4 + 3][64 + srow] = av1.w;
        sB[skq * 4 + 0][srow] = bv0.x; sB[skq * 4 + 1][srow] = bv0.y;
        sB[skq * 4 + 2][srow] = bv0.z; sB[skq * 4 + 3][srow] = bv0.w;
        sB[skq * 4 + 0][64 + srow] = bv1.x; sB[skq * 4 + 1][64 + srow] = bv1.y;
        sB[skq * 4 + 2][64 + srow] = bv1.z; sB[skq * 4 + 3][64 + srow] = bv1.w;
        __syncthreads();
        #pragma unroll
        for (int kk = 0; kk < KT; ++kk) {
            float4 am0 = *reinterpret_cast<const float4*>(&sA[kk][ty * 4]);
            float4 am1 = *reinterpret_cast<const float4*>(&sA[kk][64 + ty * 4]);
            float4 bn0 = *reinterpret_cast<const float4*>(&sB[kk][tx * 4]);
            float4 bn1 = *reinterpret_cast<const float4*>(&sB[kk][64 + tx * 4]);
            float aa[2][4] = {{am0.x, am0.y, am0.z, am0.w}, {am1.x, am1.y, am1.z, am1.w}};
            float bb[2][4] = {{bn0.x, bn0.y, bn0.z, bn0.w}, {bn1.x, bn1.y, bn1.z, bn1.w}};
            #pragma unroll
            for (int mc = 0; mc < 2; ++mc)
                #pragma unroll
                for (int nc = 0; nc < 2; ++nc)
                    #pragma unroll
                    for (int i = 0; i < 4; ++i)
                        #pragma unroll
                        for (int j = 0; j < 4; ++j)
                            c[mc][nc][i][j] = fmaf(aa[mc][i], bb[nc][j], c[mc][nc][i][j]);
        }
    }

    #pragma unroll
    for (int nc = 0; nc < 2; ++nc) {
        float4 bias = *reinterpret_cast<const float4*>(bx + tn * 128 + nc * 64 + tx * 4);
        #pragma unroll
        for (int mc = 0; mc < 2; ++mc)
            #pragma unroll
            for (int i = 0; i < 4; ++i) {
                float4 v;
                v.x = c[mc][nc][i][0] + bias.x;
                v.y = c[mc][nc][i][1] + bias.y;
                v.z = c[mc][nc][i][2] + bias.z;
                v.w = c[mc][nc][i][3] + bias.w;
                *reinterpret_cast<float4*>(
                    out + (size_t)(tm * 128 + mc * 64 + ty * 4 + i) * H_SZ
                        + tn * 128 + nc * 64 + tx * 4) = v;
            }
    }
}

// ---------------------------------------------------------------------------
// Kernel 2: serial scan, v6.
// Changes vs v5:
//  (1) __syncthreads() -> "s_waitcnt lgkmcnt(0)" + raw s_barrier.
//      __syncthreads emits s_waitcnt vmcnt(0) before s_barrier, which drained
//      the xproj prefetch loads EVERY step (full HBM/L3 latency exposed).
//      Only LDS ordering is required for correctness here: global stores are
//      never re-read, global loads are lane-private.
//  (2) xproj prefetch deepened to 2 steps (load slab t+2 at iter t, clamped),
//      so ~900cy HBM latency is covered by >=2 step bodies even across the
//      (now non-draining) barriers.
//  (3) Reduction xor4 ds_swizzle -> DPP row_half_mirror (xor 7).
//      Masks {1,2,7} are a GF(2)^3 basis -> full 8-lane butterfly, valid in
//      every lane, and bit-identical to the xor4 tree (after xor2 every lane
//      of a quad holds the quad-sum; lane^7 is in the same quad as lane^4).
//      Removes the only LDS-pipe op from the reduce critical path.
//  (4) out[t] h-stores nontemporal (never re-read; keep L2/L3 for xproj).
// ---------------------------------------------------------------------------
#define SLICE_W 40

typedef float f2 __attribute__((ext_vector_type(2)));

#define PKFMA(acc, w, h) \
    asm("v_pk_fma_f32 %0, %1, %2, %0" : "+v"(acc) : "v"(w), "v"(h))

template <int CTRL>
__device__ __forceinline__ float dpp_add(float v) {
    int y = __builtin_amdgcn_mov_dpp(__float_as_int(v), CTRL, 0xf, 0xf, true);
    return v + __int_as_float(y);
}
// Full butterfly over the 8 lanes of a ks-group: valid in every lane.
// Pure VALU: quad_perm xor1, quad_perm xor2, row_half_mirror (xor7).
__device__ __forceinline__ float red8(f2 a) {
    float v = a.x + a.y;
    v = dpp_add<0xB1>(v);     // quad_perm [1,0,3,2]  (xor 1)
    v = dpp_add<0x4E>(v);     // quad_perm [2,3,0,1]  (xor 2)
    v = dpp_add<0x141>(v);    // row_half_mirror      (xor 7)
    return v;
}
__device__ __forceinline__ float fast_tanh(float x) {
    float e = __expf(2.0f * x);
    return 1.0f - 2.0f * __builtin_amdgcn_rcpf(e + 1.0f);
}

// Barrier that does NOT drain vmcnt: only LDS ops must be complete/visible.
__device__ __forceinline__ void lds_barrier() {
    asm volatile("s_waitcnt lgkmcnt(0)" ::: "memory");
    __builtin_amdgcn_s_barrier();
    asm volatile("" ::: "memory");
}

// weight decls: w{c}_{q}l = pairs [2q], w{c}_{q}h = pairs [2q+1]
#define DECLQ(c, q) \
    f2 w##c##_##q##l = r##c[2 * (q)], w##c##_##q##h = r##c[2 * (q) + 1];
#define DECLC(c) \
    DECLQ(c,0) DECLQ(c,1) DECLQ(c,2) DECLQ(c,3) \
    DECLQ(c,4) DECLQ(c,5) DECLQ(c,6) DECLQ(c,7)

#define FMAQ(q) { \
    float4 hv = hv4[q]; \
    f2 hlo = {hv.x, hv.y}; \
    f2 hhi = {hv.z, hv.w}; \
    PKFMA(a0, w0_##q##l, hlo); PKFMA(a0, w0_##q##h, hhi); \
    PKFMA(a1, w1_##q##l, hlo); PKFMA(a1, w1_##q##h, hhi); \
    PKFMA(a2, w2_##q##l, hlo); PKFMA(a2, w2_##q##h, hhi); \
    PKFMA(a3, w3_##q##l, hlo); PKFMA(a3, w3_##q##h, hhi); }

__global__ __launch_bounds__(512)
__attribute__((amdgpu_waves_per_eu(2, 2)))
void rnn_scan(
    const float* __restrict__ h0, const float* __restrict__ Wh,
    const float* __restrict__ bh, float* __restrict__ out)
{
    __shared__ __align__(16) float hs[2][8 * SLICE_W];

    const int b    = blockIdx.x;
    const int tid  = threadIdx.x;
    const int lane = tid & 63;
    const int wave = tid >> 6;
    const int ks   = lane & 7;                 // K slice 0..7
    const int jg   = wave * 8 + (lane >> 3);   // channel group 0..63

    const f2* r0 = reinterpret_cast<const f2*>(Wh + (size_t)(jg +   0) * H_SZ + ks * 32);
    const f2* r1 = reinterpret_cast<const f2*>(Wh + (size_t)(jg +  64) * H_SZ + ks * 32);
    const f2* r2 = reinterpret_cast<const f2*>(Wh + (size_t)(jg + 128) * H_SZ + ks * 32);
    const f2* r3 = reinterpret_cast<const f2*>(Wh + (size_t)(jg + 192) * H_SZ + ks * 32);
    DECLC(0) DECLC(1) DECLC(2) DECLC(3)

    const float bj0 = bh[jg +   0];
    const float bj1 = bh[jg +  64];
    const float bj2 = bh[jg + 128];
    const float bj3 = bh[jg + 192];

    if (tid < H_SZ) {
        hs[0][(tid >> 5) * SLICE_W + (tid & 31)] = h0[(size_t)b * H_SZ + tid];
    }
    __syncthreads();

    float* __restrict__ outb = out + (size_t)b * H_SZ;
    const size_t tstr = (size_t)B_SZ * H_SZ;

    // 2-deep xproj prefetch: xp = slab t, xq = slab t+1, pre -> slab t+2.
    float xp0 = outb[jg +   0];
    float xp1 = outb[jg +  64];
    float xp2 = outb[jg + 128];
    float xp3 = outb[jg + 192];
    float xq0 = outb[tstr + jg +   0];
    float xq1 = outb[tstr + jg +  64];
    float xq2 = outb[tstr + jg + 128];
    float xq3 = outb[tstr + jg + 192];
    const float* pre = outb + 2 * tstr;

    float hn0 = 0.f, hn1 = 0.f, hn2 = 0.f, hn3 = 0.f;
    int cur = 0;
    for (int t = 0; t < L_SEQ; ++t) {
        // issue loads for slab t+2 (clamped to last valid slab)
        float n0 = pre[jg +   0];
        float n1 = pre[jg +  64];
        float n2 = pre[jg + 128];
        float n3 = pre[jg + 192];

        f2 a0 = {0.f, 0.f}, a1 = {0.f, 0.f}, a2 = {0.f, 0.f}, a3 = {0.f, 0.f};
        const float4* hv4 = reinterpret_cast<const float4*>(&hs[cur][ks * SLICE_W]);
        FMAQ(0) FMAQ(1) FMAQ(2) FMAQ(3) FMAQ(4) FMAQ(5) FMAQ(6) FMAQ(7)

        float s0 = red8(a0);
        float s1 = red8(a1);
        float s2 = red8(a2);
        float s3 = red8(a3);

        hn0 = fast_tanh(xp0 + bj0 + s0);
        hn1 = fast_tanh(xp1 + bj1 + s1);
        hn2 = fast_tanh(xp2 + bj2 + s2);
        hn3 = fast_tanh(xp3 + bj3 + s3);

        if (ks == 0) {
            const size_t tb = (size_t)t * tstr;
            __builtin_nontemporal_store(hn0, &outb[tb + jg +   0]);
            __builtin_nontemporal_store(hn1, &outb[tb + jg +  64]);
            __builtin_nontemporal_store(hn2, &outb[tb + jg + 128]);
            __builtin_nontemporal_store(hn3, &outb[tb + jg + 192]);
            float* hw = hs[cur ^ 1];
            const int base = (jg >> 5) * SLICE_W + (jg & 31);
            hw[base + 0 * (2 * SLICE_W)] = hn0;
            hw[base + 1 * (2 * SLICE_W)] = hn1;
            hw[base + 2 * (2 * SLICE_W)] = hn2;
            hw[base + 3 * (2 * SLICE_W)] = hn3;
        }
        // LDS-only barrier: global prefetch loads stay in flight.
        lds_barrier();
        cur ^= 1;
        xp0 = xq0; xp1 = xq1; xp2 = xq2; xp3 = xq3;
        xq0 = n0;  xq1 = n1;  xq2 = n2;  xq3 = n3;
        if (t + 3 < L_SEQ) pre += tstr;   // clamp: stay in-bounds at the tail
    }

    if (ks == 0) {
        float* hf = out + (size_t)L_SEQ * tstr + (size_t)b * H_SZ;
        hf[jg +   0] = hn0;
        hf[jg +  64] = hn1;
        hf[jg + 128] = hn2;
        hf[jg + 192] = hn3;
    }
}

extern "C" void kernel_launch(void* const* d_in, const int* in_sizes, int n_in,
                              void* d_out, int out_size, void* d_ws, size_t ws_size,
                              hipStream_t stream) {
    const float* x    = (const float*)d_in[0];   // [L,B,D]
    const float* h0   = (const float*)d_in[1];   // [B,H]
    const float* Wx_w = (const float*)d_in[2];   // [H,D]
    const float* Wx_b = (const float*)d_in[3];   // [H]
    const float* Wh_w = (const float*)d_in[4];   // [H,H]
    const float* Wh_b = (const float*)d_in[5];   // [H]
    float* out = (float*)d_out;                  // [L,B,H] ++ [B,H]

    (void)in_sizes; (void)n_in; (void)d_ws; (void)ws_size; (void)out_size;

    dim3 grid1((L_SEQ * B_SZ) / 128, H_SZ / 128);
    xproj_gemm<<<grid1, 256, 0, stream>>>(x, Wx_w, Wx_b, out);

    rnn_scan<<<dim3(B_SZ), 512, 0, stream>>>(h0, Wh_w, Wh_b, out);
}

// Round 2
// 1024.987 us; speedup vs baseline: 1.0876x; 1.0730x over previous
//
#include <hip/hip_runtime.h>
#include <cstddef>

#define L_SEQ 1024
#define B_SZ  128
#define D_SZ  256
#define H_SZ  256

// ---------------------------------------------------------------------------
// Kernel 1: xproj GEMM (unchanged -- control)
// ---------------------------------------------------------------------------
#define KT  16
#define LDA 132

__global__ __launch_bounds__(256) void xproj_gemm(
    const float* __restrict__ x, const float* __restrict__ Wx,
    const float* __restrict__ bx, float* __restrict__ out)
{
    __shared__ float sA[KT][LDA];
    __shared__ float sB[KT][LDA];

    const int tm  = blockIdx.x;
    const int tn  = blockIdx.y;
    const int tid = threadIdx.x;
    const int tx  = tid & 15;
    const int ty  = tid >> 4;
    const int srow = tid >> 2;
    const int skq  = tid & 3;

    const float* __restrict__ Ag = x  + (size_t)(tm * 128 + srow) * D_SZ + skq * 4;
    const float* __restrict__ Bg = Wx + (size_t)(tn * 128 + srow) * D_SZ + skq * 4;

    float c[2][2][4][4];
    #pragma unroll
    for (int mc = 0; mc < 2; ++mc)
        #pragma unroll
        for (int nc = 0; nc < 2; ++nc)
            #pragma unroll
            for (int i = 0; i < 4; ++i)
                #pragma unroll
                for (int j = 0; j < 4; ++j) c[mc][nc][i][j] = 0.0f;

    for (int kt = 0; kt < D_SZ / KT; ++kt) {
        float4 av0 = *reinterpret_cast<const float4*>(Ag + kt * KT);
        float4 av1 = *reinterpret_cast<const float4*>(Ag + (size_t)64 * D_SZ + kt * KT);
        float4 bv0 = *reinterpret_cast<const float4*>(Bg + kt * KT);
        float4 bv1 = *reinterpret_cast<const float4*>(Bg + (size_t)64 * D_SZ + kt * KT);
        __syncthreads();
        sA[skq * 4 + 0][srow] = av0.x; sA[skq * 4 + 1][srow] = av0.y;
        sA[skq * 4 + 2][srow] = av0.z; sA[skq * 4 + 3][srow] = av0.w;
        sA[skq * 4 + 0][64 + srow] = av1.x; sA[skq * 4 + 1][64 + srow] = av1.y;
        sA[skq * 4 + 2][64 + srow] = av1.z; sA[skq * 4 + 3][64 + srow] = av1.w;
        sB[skq * 4 + 0][srow] = bv0.x; sB[skq * 4 + 1][srow] = bv0.y;
        sB[skq * 4 + 2][srow] = bv0.z; sB[skq * 4 + 3][srow] = bv0.w;
        sB[skq * 4 + 0][64 + srow] = bv1.x; sB[skq * 4 + 1][64 + srow] = bv1.y;
        sB[skq * 4 + 2][64 + srow] = bv1.z; sB[skq * 4 + 3][64 + srow] = bv1.w;
        __syncthreads();
        #pragma unroll
        for (int kk = 0; kk < KT; ++kk) {
            float4 am0 = *reinterpret_cast<const float4*>(&sA[kk][ty * 4]);
            float4 am1 = *reinterpret_cast<const float4*>(&sA[kk][64 + ty * 4]);
            float4 bn0 = *reinterpret_cast<const float4*>(&sB[kk][tx * 4]);
            float4 bn1 = *reinterpret_cast<const float4*>(&sB[kk][64 + tx * 4]);
            float aa[2][4] = {{am0.x, am0.y, am0.z, am0.w}, {am1.x, am1.y, am1.z, am1.w}};
            float bb[2][4] = {{bn0.x, bn0.y, bn0.z, bn0.w}, {bn1.x, bn1.y, bn1.z, bn1.w}};
            #pragma unroll
            for (int mc = 0; mc < 2; ++mc)
                #pragma unroll
                for (int nc = 0; nc < 2; ++nc)
                    #pragma unroll
                    for (int i = 0; i < 4; ++i)
                        #pragma unroll
                        for (int j = 0; j < 4; ++j)
                            c[mc][nc][i][j] = fmaf(aa[mc][i], bb[nc][j], c[mc][nc][i][j]);
        }
    }

    #pragma unroll
    for (int nc = 0; nc < 2; ++nc) {
        float4 bias = *reinterpret_cast<const float4*>(bx + tn * 128 + nc * 64 + tx * 4);
        #pragma unroll
        for (int mc = 0; mc < 2; ++mc)
            #pragma unroll
            for (int i = 0; i < 4; ++i) {
                float4 v;
                v.x = c[mc][nc][i][0] + bias.x;
                v.y = c[mc][nc][i][1] + bias.y;
                v.z = c[mc][nc][i][2] + bias.z;
                v.w = c[mc][nc][i][3] + bias.w;
                *reinterpret_cast<float4*>(
                    out + (size_t)(tm * 128 + mc * 64 + ty * 4 + i) * H_SZ
                        + tn * 128 + nc * 64 + tx * 4) = v;
            }
    }
}

// ---------------------------------------------------------------------------
// Kernel 2: serial scan, v7.
// Change vs v6: HAND-UNROLL x2 with two named xp register sets (xa*, xb*).
// v6's rotation (xp=xq; xq=n) was a register COPY of the freshly-loaded
// value -> the compiler had to s_waitcnt vmcnt inside the SAME iteration,
// nullifying the prefetch depth (exposed ~900cy HBM latency every step,
// since half the xproj stream misses L3 -- FETCH=66MB of 134MB).
// With the unroll, the load for slab t+2 writes DIRECTLY into the register
// consumed at iteration t+2 (no copies, no same-iteration wait): first touch
// is 2 full bodies (~>=1600cy) later. u = xp + bias is computed at body top
// so the WAR hazard releases immediately and loads issue early.
// ---------------------------------------------------------------------------
#define SLICE_W 40

typedef float f2 __attribute__((ext_vector_type(2)));

#define PKFMA(acc, w, h) \
    asm("v_pk_fma_f32 %0, %1, %2, %0" : "+v"(acc) : "v"(w), "v"(h))

template <int CTRL>
__device__ __forceinline__ float dpp_add(float v) {
    int y = __builtin_amdgcn_mov_dpp(__float_as_int(v), CTRL, 0xf, 0xf, true);
    return v + __int_as_float(y);
}
// Full butterfly over the 8 lanes of a ks-group: valid in every lane.
// Pure VALU: quad_perm xor1, quad_perm xor2, row_half_mirror (xor7).
__device__ __forceinline__ float red8(f2 a) {
    float v = a.x + a.y;
    v = dpp_add<0xB1>(v);     // quad_perm [1,0,3,2]  (xor 1)
    v = dpp_add<0x4E>(v);     // quad_perm [2,3,0,1]  (xor 2)
    v = dpp_add<0x141>(v);    // row_half_mirror      (xor 7)
    return v;
}
__device__ __forceinline__ float fast_tanh(float x) {
    float e = __expf(2.0f * x);
    return 1.0f - 2.0f * __builtin_amdgcn_rcpf(e + 1.0f);
}

// Barrier that does NOT drain vmcnt: only LDS ops must be complete/visible.
__device__ __forceinline__ void lds_barrier() {
    asm volatile("s_waitcnt lgkmcnt(0)" ::: "memory");
    __builtin_amdgcn_s_barrier();
    asm volatile("" ::: "memory");
}

// weight decls: w{c}_{q}l = pairs [2q], w{c}_{q}h = pairs [2q+1]
#define DECLQ(c, q) \
    f2 w##c##_##q##l = r##c[2 * (q)], w##c##_##q##h = r##c[2 * (q) + 1];
#define DECLC(c) \
    DECLQ(c,0) DECLQ(c,1) DECLQ(c,2) DECLQ(c,3) \
    DECLQ(c,4) DECLQ(c,5) DECLQ(c,6) DECLQ(c,7)

#define FMAQ(q) { \
    float4 hv = hv4[q]; \
    f2 hlo = {hv.x, hv.y}; \
    f2 hhi = {hv.z, hv.w}; \
    PKFMA(a0, w0_##q##l, hlo); PKFMA(a0, w0_##q##h, hhi); \
    PKFMA(a1, w1_##q##l, hlo); PKFMA(a1, w1_##q##h, hhi); \
    PKFMA(a2, w2_##q##l, hlo); PKFMA(a2, w2_##q##h, hhi); \
    PKFMA(a3, w3_##q##l, hlo); PKFMA(a3, w3_##q##h, hhi); }

// One scan step. SRC/DST are compile-time LDS buffer indices.
// X0..X3 are the xproj registers for THIS step; after their value is
// captured into u*, the slab for step T+2 is loaded directly into them
// (no copies -> no same-iteration vmcnt wait).
#define BODY(T, SRC, DST, X0, X1, X2, X3) { \
    float u0 = X0 + bj0, u1 = X1 + bj1, u2 = X2 + bj2, u3 = X3 + bj3; \
    { \
        const int tnext = (T) + 2 < L_SEQ ? (T) + 2 : L_SEQ - 1; \
        const size_t t2 = (size_t)tnext * tstr; \
        X0 = outb[t2 + jg +   0]; \
        X1 = outb[t2 + jg +  64]; \
        X2 = outb[t2 + jg + 128]; \
        X3 = outb[t2 + jg + 192]; \
    } \
    f2 a0 = {0.f, 0.f}, a1 = {0.f, 0.f}, a2 = {0.f, 0.f}, a3 = {0.f, 0.f}; \
    const float4* hv4 = reinterpret_cast<const float4*>(&hs[SRC][ks * SLICE_W]); \
    FMAQ(0) FMAQ(1) FMAQ(2) FMAQ(3) FMAQ(4) FMAQ(5) FMAQ(6) FMAQ(7) \
    float s0 = red8(a0); \
    float s1 = red8(a1); \
    float s2 = red8(a2); \
    float s3 = red8(a3); \
    hn0 = fast_tanh(u0 + s0); \
    hn1 = fast_tanh(u1 + s1); \
    hn2 = fast_tanh(u2 + s2); \
    hn3 = fast_tanh(u3 + s3); \
    if (ks == 0) { \
        const size_t tb = (size_t)(T) * tstr; \
        __builtin_nontemporal_store(hn0, &outb[tb + jg +   0]); \
        __builtin_nontemporal_store(hn1, &outb[tb + jg +  64]); \
        __builtin_nontemporal_store(hn2, &outb[tb + jg + 128]); \
        __builtin_nontemporal_store(hn3, &outb[tb + jg + 192]); \
        float* hw = hs[DST]; \
        const int base = (jg >> 5) * SLICE_W + (jg & 31); \
        hw[base + 0 * (2 * SLICE_W)] = hn0; \
        hw[base + 1 * (2 * SLICE_W)] = hn1; \
        hw[base + 2 * (2 * SLICE_W)] = hn2; \
        hw[base + 3 * (2 * SLICE_W)] = hn3; \
    } \
    lds_barrier(); \
}

__global__ __launch_bounds__(512)
__attribute__((amdgpu_waves_per_eu(2, 2)))
void rnn_scan(
    const float* __restrict__ h0, const float* __restrict__ Wh,
    const float* __restrict__ bh, float* __restrict__ out)
{
    __shared__ __align__(16) float hs[2][8 * SLICE_W];

    const int b    = blockIdx.x;
    const int tid  = threadIdx.x;
    const int lane = tid & 63;
    const int wave = tid >> 6;
    const int ks   = lane & 7;                 // K slice 0..7
    const int jg   = wave * 8 + (lane >> 3);   // channel group 0..63

    const f2* r0 = reinterpret_cast<const f2*>(Wh + (size_t)(jg +   0) * H_SZ + ks * 32);
    const f2* r1 = reinterpret_cast<const f2*>(Wh + (size_t)(jg +  64) * H_SZ + ks * 32);
    const f2* r2 = reinterpret_cast<const f2*>(Wh + (size_t)(jg + 128) * H_SZ + ks * 32);
    const f2* r3 = reinterpret_cast<const f2*>(Wh + (size_t)(jg + 192) * H_SZ + ks * 32);
    DECLC(0) DECLC(1) DECLC(2) DECLC(3)

    const float bj0 = bh[jg +   0];
    const float bj1 = bh[jg +  64];
    const float bj2 = bh[jg + 128];
    const float bj3 = bh[jg + 192];

    if (tid < H_SZ) {
        hs[0][(tid >> 5) * SLICE_W + (tid & 31)] = h0[(size_t)b * H_SZ + tid];
    }
    __syncthreads();

    float* __restrict__ outb = out + (size_t)b * H_SZ;
    const size_t tstr = (size_t)B_SZ * H_SZ;

    // Prologue: set A = slab 0 (even steps), set B = slab 1 (odd steps).
    float xa0 = outb[jg +   0];
    float xa1 = outb[jg +  64];
    float xa2 = outb[jg + 128];
    float xa3 = outb[jg + 192];
    float xb0 = outb[tstr + jg +   0];
    float xb1 = outb[tstr + jg +  64];
    float xb2 = outb[tstr + jg + 128];
    float xb3 = outb[tstr + jg + 192];

    float hn0 = 0.f, hn1 = 0.f, hn2 = 0.f, hn3 = 0.f;
    for (int t = 0; t < L_SEQ; t += 2) {
        BODY(t,     0, 1, xa0, xa1, xa2, xa3)
        BODY(t + 1, 1, 0, xb0, xb1, xb2, xb3)
    }

    if (ks == 0) {
        float* hf = out + (size_t)L_SEQ * tstr + (size_t)b * H_SZ;
        hf[jg +   0] = hn0;
        hf[jg +  64] = hn1;
        hf[jg + 128] = hn2;
        hf[jg + 192] = hn3;
    }
}

extern "C" void kernel_launch(void* const* d_in, const int* in_sizes, int n_in,
                              void* d_out, int out_size, void* d_ws, size_t ws_size,
                              hipStream_t stream) {
    const float* x    = (const float*)d_in[0];   // [L,B,D]
    const float* h0   = (const float*)d_in[1];   // [B,H]
    const float* Wx_w = (const float*)d_in[2];   // [H,D]
    const float* Wx_b = (const float*)d_in[3];   // [H]
    const float* Wh_w = (const float*)d_in[4];   // [H,H]
    const float* Wh_b = (const float*)d_in[5];   // [H]
    float* out = (float*)d_out;                  // [L,B,H] ++ [B,H]

    (void)in_sizes; (void)n_in; (void)d_ws; (void)ws_size; (void)out_size;

    dim3 grid1((L_SEQ * B_SZ) / 128, H_SZ / 128);
    xproj_gemm<<<grid1, 256, 0, stream>>>(x, Wx_w, Wx_b, out);

    rnn_scan<<<dim3(B_SZ), 512, 0, stream>>>(h0, Wh_w, Wh_b, out);
}